// Round 1
// 518.879 us; speedup vs baseline: 1.3362x; 1.3362x over previous
//
#include <hip/hip_runtime.h>
#include <stdint.h>

typedef _Float16 half_t;
typedef _Float16 half8  __attribute__((ext_vector_type(8)));
typedef _Float16 half4v __attribute__((ext_vector_type(4)));
typedef _Float16 half2v __attribute__((ext_vector_type(2)));
typedef float    floatx4 __attribute__((ext_vector_type(4)));

#define NTOK 49
#define DIM  128
#define HEADS 4

// LDS (halfs), 40768 B total -> 4 blocks/CU:
//  XH : [49][128] fp16, XOR-swizzled 16B granules. x staging, then attn-out staging.
//  QK : per head [49][72]: q in cols 0..31, k in cols 32..63, pad 64..71.
//       P [16][72] aliases QK rows 0..15 during phase 3 (kf preloaded, qf[0] read first).
#define XH_HALFS  (NTOK * 128)                       // 6272
#define QK_STRIDE 72
#define QK_HALFS  (NTOK * QK_STRIDE)                 // 3528
#define SMEM_HALFS (XH_HALFS + HEADS * QK_HALFS)     // 20384 halfs = 40768 B

// swizzle: stride 128 rows, XOR bits 3..5 of the half-index with tok&7
// -> every 16-lane column-slice read/write lands on 8 distinct 16B slots (2-way max).
#define XH_IDX(tok, h) ((tok) * 128 + ((h) ^ (((tok) & 7) << 3)))

#define MFMA16(a, b, c) __builtin_amdgcn_mfma_f32_16x16x32_f16((a), (b), (c), 0, 0, 0)

// Row-clamp for all token-indexed LDS reads: rows 49..63 are never written;
// clamping to 48 keeps every read on written data (bit-deterministic).
#define CLAMP48(r_) ((r_) < 48 ? (r_) : 48)

union HW { uint32_t w[4]; half8 h; };

__device__ inline half8 cvt8(const float* __restrict__ p) {
    float4 w0 = *(const float4*)p;
    float4 w1 = *(const float4*)(p + 4);
    half8 r;
    r[0] = (half_t)w0.x; r[1] = (half_t)w0.y; r[2] = (half_t)w0.z; r[3] = (half_t)w0.w;
    r[4] = (half_t)w1.x; r[5] = (half_t)w1.y; r[6] = (half_t)w1.z; r[7] = (half_t)w1.w;
    return r;
}

__device__ inline uint32_t pkh2(float a, float b) {
    union { half2v h; uint32_t u; } c;
    c.h[0] = (half_t)a; c.h[1] = (half_t)b;   // RTN, identical to old LDS path
    return c.u;
}

// Pre-convert qkv_w (384x128) + proj_w (128x128) to fp16 in workspace.
__global__ __launch_bounds__(256)
void cvtw(const float* __restrict__ qw, const float* __restrict__ pw,
          half_t* __restrict__ o) {
    int i = blockIdx.x * 256 + threadIdx.x;          // 16384 threads, one float4 each
    float4 v = (i < 12288) ? ((const float4*)qw)[i] : ((const float4*)pw)[i - 12288];
    half4v h;
    h[0] = (half_t)v.x; h[1] = (half_t)v.y; h[2] = (half_t)v.z; h[3] = (half_t)v.w;
    *(half4v*)(o + 4 * i) = h;
}

template <bool W16>
__global__ __launch_bounds__(256, 4)
void winattn(const float* __restrict__ x, const float* __restrict__ qkv_w,
             const float* __restrict__ qkv_b, const float* __restrict__ proj_w,
             const float* __restrict__ proj_b, const float* __restrict__ bias_table,
             const half_t* __restrict__ w16, float* __restrict__ out, int nwin)
{
    __shared__ __attribute__((aligned(16))) half_t smem[SMEM_HALFS];
    const int tid  = threadIdx.x;
    const int wid  = tid >> 6;        // wave id == head id
    const int lane = tid & 63;
    const int quad = lane >> 4;
    const int cl   = lane & 15;
    const int win  = blockIdx.x;
    if (win >= nwin) return;

    const floatx4 Z4 = {0.f, 0.f, 0.f, 0.f};
    half_t* const qkh = smem + XH_HALFS + wid * QK_HALFS;

    // ---------------- phase 1: stage x window as fp16 (swizzled) ----------------
    const float* xp = x + (size_t)win * (NTOK * DIM);
    for (int i4 = tid; i4 < NTOK * DIM / 4; i4 += 256) {
        float4 v = ((const float4*)xp)[i4];
        int f = i4 << 2, tok = f >> 7, ch = f & 127;
        half4v h;
        h[0] = (half_t)v.x; h[1] = (half_t)v.y; h[2] = (half_t)v.z; h[3] = (half_t)v.w;
        *(half4v*)(smem + XH_IDX(tok, ch)) = h;
    }
    __syncthreads();

    // ---------------- phase 2: QKV GEMM (per wave: its head's q,k,v cols) -------
    half8 a[4][4];
#pragma unroll
    for (int mt = 0; mt < 4; ++mt) {
        const int ar = CLAMP48(mt * 16 + cl);
#pragma unroll
        for (int ks = 0; ks < 4; ++ks)
            a[mt][ks] = *(const half8*)(smem + XH_IDX(ar, ks * 32 + quad * 8));
    }
    // After this barrier XH is free for attn-out staging; phases 2-3 are
    // fully wave-local (q/k/v buffers are per-head private).
    __syncthreads();

    half8 vf[2][2];   // v fragments [ks][ch16], built in-register (no vT LDS)
    const float scale = 0.17677669529663687f;  // 32^-0.5
#pragma unroll
    for (int cg = 0; cg < 6; ++cg) {
        const int typ  = cg >> 1;   // 0=q 1=k 2=v
        const int ch16 = cg & 1;
        const int n    = typ * 128 + wid * 32 + ch16 * 16 + cl;
        floatx4 acc[4];
#pragma unroll
        for (int mt = 0; mt < 4; ++mt) acc[mt] = Z4;
#pragma unroll
        for (int ks = 0; ks < 4; ++ks) {
            half8 b;
            if constexpr (W16) b = *(const half8*)(w16 + n * DIM + ks * 32 + quad * 8);
            else               b = cvt8(qkv_w + n * DIM + ks * 32 + quad * 8);
#pragma unroll
            for (int mt = 0; mt < 4; ++mt) acc[mt] = MFMA16(a[mt][ks], b, acc[mt]);
        }
        const float bias = qkv_b[n];
        const int lc = ch16 * 16 + cl;
        if (typ == 0) {
#pragma unroll
            for (int mt = 0; mt < 4; ++mt)
#pragma unroll
                for (int r = 0; r < 4; ++r) {
                    int tok = mt * 16 + quad * 4 + r;
                    if (tok < NTOK) qkh[tok * QK_STRIDE + lc] = (half_t)((acc[mt][r] + bias) * scale);
                }
        } else if (typ == 1) {
#pragma unroll
            for (int mt = 0; mt < 4; ++mt)
#pragma unroll
                for (int r = 0; r < 4; ++r) {
                    int tok = mt * 16 + quad * 4 + r;
                    if (tok < NTOK) qkh[tok * QK_STRIDE + 32 + lc] = (half_t)(acc[mt][r] + bias);
                }
        } else {
            // v: transpose token dim across quads via shuffles, keep in registers.
            // Producer: lane(qs,cl) holds v[t=mt*16+qs*4+r][ch=ch16*16+cl].
            // Consumer vf[k2][ch16] half j: v[t=k2*32+8*quad+j][ch=ch16*16+cl]
            //  -> src lane qs = (2*quad + (j>>2)) & 3 (same cl), reg mt = 2*k2+(quad>>1), r=j&3.
            uint32_t p0[4], p1[4];
#pragma unroll
            for (int mt = 0; mt < 4; ++mt) {
                p0[mt] = pkh2(acc[mt][0] + bias, acc[mt][1] + bias);
                p1[mt] = pkh2(acc[mt][2] + bias, acc[mt][3] + bias);
            }
            const int s0 = ((quad << 1) & 3) * 16 + cl;
            const int s1 = (((quad << 1) | 1) & 3) * 16 + cl;
            const bool hiq = quad >= 2;
#pragma unroll
            for (int k2 = 0; k2 < 2; ++k2) {
                int aA = __shfl((int)p0[2 * k2], s0),     aB = __shfl((int)p0[2 * k2 + 1], s0);
                int bA = __shfl((int)p1[2 * k2], s0),     bB = __shfl((int)p1[2 * k2 + 1], s0);
                int cA = __shfl((int)p0[2 * k2], s1),     cB = __shfl((int)p0[2 * k2 + 1], s1);
                int dA = __shfl((int)p1[2 * k2], s1),     dB = __shfl((int)p1[2 * k2 + 1], s1);
                HW u;
                u.w[0] = (uint32_t)(hiq ? aB : aA);
                u.w[1] = (uint32_t)(hiq ? bB : bA);
                u.w[2] = (uint32_t)(hiq ? cB : cA);
                u.w[3] = (uint32_t)(hiq ? dB : dA);
                vf[k2][ch16] = u.h;
            }
        }
    }
    // No barrier: q/k in LDS and vf in regs are wave-private. Pad v tokens 49..63
    // are finite row-48 dups; they meet exactly-zero P columns, so no re-zeroing.

    // ---------------- phase 3: attention for head = wid ----------------
    int K1[4];
#pragma unroll
    for (int nt = 0; nt < 4; ++nt) {
        int colc = CLAMP48(nt * 16 + cl);
        int kr   = (colc * 37) >> 8;        // colc / 7 (valid for 0..48)
        int kc   = colc - kr * 7;
        K1[nt]   = kr * 13 + kc;
    }
    const bool cm3 = (cl == 0);  // N-tile 3: only col 48 is a valid key

    half8 kf[4];
#pragma unroll
    for (int nt = 0; nt < 4; ++nt)
        kf[nt] = *(const half8*)(qkh + CLAMP48(nt * 16 + cl) * QK_STRIDE + 32 + quad * 8);

    half_t* const Pb = qkh;   // alias QK rows 0..15 (kf consumed; qf[0] read before stores)
    const float* bt = bias_table;

#pragma unroll
    for (int mt = 0; mt < 4; ++mt) {
        half8 qf = *(const half8*)(qkh + CLAMP48(mt * 16 + cl) * QK_STRIDE + quad * 8);
        floatx4 s[4];
#pragma unroll
        for (int nt = 0; nt < 4; ++nt)
            s[nt] = MFMA16(qf, kf[nt], Z4);

        float sv[4][4];
#pragma unroll
        for (int r = 0; r < 4; ++r) {
            int tc  = CLAMP48(mt * 16 + quad * 4 + r);
            int qr  = (tc * 37) >> 8;
            int qc  = tc - qr * 7;
            int Q1  = qr * 13 + qc + 84;
#pragma unroll
            for (int nt = 0; nt < 4; ++nt)
                sv[nt][r] = s[nt][r] + bt[(Q1 - K1[nt]) * HEADS + wid];
        }
#pragma unroll
        for (int r = 0; r < 4; ++r) sv[3][r] = cm3 ? sv[3][r] : -1e30f;

        float mx[4], sum[4], ex[4][4];
#pragma unroll
        for (int r = 0; r < 4; ++r)
            mx[r] = fmaxf(fmaxf(sv[0][r], sv[1][r]), fmaxf(sv[2][r], sv[3][r]));
#pragma unroll
        for (int off = 1; off < 16; off <<= 1)
#pragma unroll
            for (int r = 0; r < 4; ++r) mx[r] = fmaxf(mx[r], __shfl_xor(mx[r], off, 16));
#pragma unroll
        for (int r = 0; r < 4; ++r) {
            sum[r] = 0.f;
#pragma unroll
            for (int nt = 0; nt < 4; ++nt) {
                float e = __expf(sv[nt][r] - mx[r]);
                ex[nt][r] = e;
                sum[r] += e;
            }
        }
#pragma unroll
        for (int off = 1; off < 16; off <<= 1)
#pragma unroll
            for (int r = 0; r < 4; ++r) sum[r] += __shfl_xor(sum[r], off, 16);

#pragma unroll
        for (int r = 0; r < 4; ++r) {
            float rinv = 1.0f / sum[r];
#pragma unroll
            for (int nt = 0; nt < 4; ++nt)
                Pb[(quad * 4 + r) * QK_STRIDE + nt * 16 + cl] = (half_t)(ex[nt][r] * rinv);
        }

        half8 pf0 = *(const half8*)(Pb + cl * QK_STRIDE + quad * 8);
        half8 pf1 = *(const half8*)(Pb + cl * QK_STRIDE + 32 + quad * 8);
        floatx4 o0 = Z4, o1 = Z4;
        o0 = MFMA16(pf0, vf[0][0], o0); o0 = MFMA16(pf1, vf[1][0], o0);
        o1 = MFMA16(pf0, vf[0][1], o1); o1 = MFMA16(pf1, vf[1][1], o1);

#pragma unroll
        for (int r = 0; r < 4; ++r) {
            int tok = mt * 16 + quad * 4 + r;
            if (tok < NTOK) {
                smem[XH_IDX(tok, wid * 32 + cl)]      = (half_t)o0[r];
                smem[XH_IDX(tok, wid * 32 + 16 + cl)] = (half_t)o1[r];
            }
        }
    }
    __syncthreads();  // attn-out staging complete for all heads

    // ---------------- phase 5: proj GEMM ----------------
    half8 pwf[2][4];
    const int nbase = wid * 32;
#pragma unroll
    for (int nt = 0; nt < 2; ++nt)
#pragma unroll
        for (int ks = 0; ks < 4; ++ks) {
            if constexpr (W16)
                pwf[nt][ks] = *(const half8*)(w16 + 3 * DIM * DIM +
                                              (nbase + nt * 16 + cl) * DIM + ks * 32 + quad * 8);
            else
                pwf[nt][ks] = cvt8(proj_w + (nbase + nt * 16 + cl) * DIM + ks * 32 + quad * 8);
        }
    float pb0 = proj_b[nbase + cl];
    float pb1 = proj_b[nbase + 16 + cl];

    float* ow = out + (size_t)win * (NTOK * DIM);
#pragma unroll
    for (int mt = 0; mt < 4; ++mt) {
        floatx4 a0 = Z4, a1 = Z4;
        const int ar = CLAMP48(mt * 16 + cl);
#pragma unroll
        for (int ks = 0; ks < 4; ++ks) {
            half8 af = *(const half8*)(smem + XH_IDX(ar, ks * 32 + quad * 8));
            a0 = MFMA16(af, pwf[0][ks], a0);
            a1 = MFMA16(af, pwf[1][ks], a1);
        }
#pragma unroll
        for (int r = 0; r < 4; ++r) {
            int tok = mt * 16 + quad * 4 + r;
            if (tok < NTOK) {
                ow[tok * DIM + nbase + cl]      = a0[r] + pb0;
                ow[tok * DIM + nbase + 16 + cl] = a1[r] + pb1;
            }
        }
    }
}

extern "C" void kernel_launch(void* const* d_in, const int* in_sizes, int n_in,
                              void* d_out, int out_size, void* d_ws, size_t ws_size,
                              hipStream_t stream) {
    const float* x          = (const float*)d_in[0];
    const float* qkv_w      = (const float*)d_in[1];
    const float* qkv_b      = (const float*)d_in[2];
    const float* proj_w     = (const float*)d_in[3];
    const float* proj_b     = (const float*)d_in[4];
    const float* bias_table = (const float*)d_in[5];
    // d_in[6] (rel_index) is recomputed analytically in-kernel.
    const int nwin = in_sizes[0] / (NTOK * DIM);
    const size_t wbytes = (size_t)(3 * DIM * DIM + DIM * DIM) * sizeof(half_t); // 131072 B
    if (d_ws && ws_size >= wbytes) {
        half_t* w16 = (half_t*)d_ws;
        cvtw<<<64, 256, 0, stream>>>(qkv_w, proj_w, w16);
        winattn<true><<<nwin, 256, 0, stream>>>(x, qkv_w, qkv_b, proj_w, proj_b,
                                                bias_table, w16, (float*)d_out, nwin);
    } else {
        winattn<false><<<nwin, 256, 0, stream>>>(x, qkv_w, qkv_b, proj_w, proj_b,
                                                 bias_table, nullptr, (float*)d_out, nwin);
    }
}